// Round 1
// baseline (1992.718 us; speedup 1.0000x reference)
//
#include <hip/hip_runtime.h>
#include <hip/hip_bf16.h>
#include <math.h>

namespace {

constexpr int kB  = 32;
constexpr int kL  = 1024;
constexpr int kH  = 512;
constexpr int kP  = 336;
constexpr int kNL = 3;
constexpr int kNS = 32;
constexpr int kH2 = 2 * kH;

// ---------------------------------------------------------------------------
// K0: SSM discretization params. r = exp(dt*A); Ct2 = 2*(C * expm1(dt*A)/A)
// ---------------------------------------------------------------------------
__global__ void ssm_params_kernel(const float* __restrict__ log_dt,
                                  const float* __restrict__ A_re,
                                  const float* __restrict__ A_im,
                                  const float* __restrict__ C_re,
                                  const float* __restrict__ C_im,
                                  float* __restrict__ prr, float* __restrict__ pri,
                                  float* __restrict__ pcr, float* __restrict__ pci) {
  int idx = blockIdx.x * blockDim.x + threadIdx.x;
  if (idx >= kNL * kH * kNS) return;
  int lh = idx / kNS;  // layer*H + h
  float dt = expf(log_dt[lh]);
  float ar = A_re[idx], ai = A_im[idx];
  float dr = dt * ar, di = dt * ai;
  float er = expf(dr);
  float c = cosf(di), s = sinf(di);
  float rr = er * c, ri = er * s;
  // expm1(dtA): accurate real part = expm1(dr)*cos(di) - 2*sin^2(di/2)
  float sh = sinf(0.5f * di);
  float mr = expm1f(dr) * c - 2.f * sh * sh;
  float mi = ri;
  // q = expm1(dtA) / A  (complex divide via conj)
  float inv = 1.f / (ar * ar + ai * ai);
  float qr = (mr * ar + mi * ai) * inv;
  float qi = (mi * ar - mr * ai) * inv;
  float cre = C_re[idx], cim = C_im[idx];
  prr[idx] = rr;
  pri[idx] = ri;
  pcr[idx] = 2.f * (cre * qr - cim * qi);
  pci[idx] = 2.f * (cre * qi + cim * qr);
}

// ---------------------------------------------------------------------------
// K1: (B, L, E) -> (B, E, L) transpose, 32x32 LDS tiles
// ---------------------------------------------------------------------------
__global__ __launch_bounds__(256) void transpose_kernel(const float* __restrict__ x,
                                                        float* __restrict__ u) {
  __shared__ float tile[32][33];
  int b = blockIdx.z;
  int l0 = blockIdx.x * 32, e0 = blockIdx.y * 32;
  int tx = threadIdx.x, ty = threadIdx.y;  // (32, 8)
#pragma unroll
  for (int k = 0; k < 4; k++)
    tile[ty + 8 * k][tx] = x[((size_t)b * kL + (size_t)(l0 + ty + 8 * k)) * kH + e0 + tx];
  __syncthreads();
#pragma unroll
  for (int k = 0; k < 4; k++)
    u[((size_t)b * kH + (size_t)(e0 + ty + 8 * k)) * kL + l0 + tx] = tile[tx][ty + 8 * k];
}

__device__ __forceinline__ float f4get(const float4& v, int i) {
  return (i == 0) ? v.x : (i == 1) ? v.y : (i == 2) ? v.z : v.w;
}

// ---------------------------------------------------------------------------
// K2: diagonal SSM recurrence + D-skip + GELU(tanh).
// 4 lanes per (b,h) row, 8 complex states per lane; reduction over n is
// 2 shfl_xor per step. u read as broadcast float4, prefetched 16 steps ahead.
// grid = B*H/64 blocks of 256 threads (16 rows per wave).
// ---------------------------------------------------------------------------
__global__ __launch_bounds__(256) void s4_scan_kernel(
    const float* __restrict__ uin, float* __restrict__ yout,
    const float* __restrict__ prr, const float* __restrict__ pri,
    const float* __restrict__ pcr, const float* __restrict__ pci,
    const float* __restrict__ Dskip, int layer) {
  int tid = threadIdx.x;
  int g = (blockIdx.x << 6) + (tid >> 2);  // (b,h) row id in [0, B*H)
  int j = tid & 3;                         // lane within 4-lane group
  int h = g & (kH - 1);

  float rr[8], ri[8], cr[8], ci[8], xr[8], xi[8];
  int base = ((layer * kH + h) << 5) + (j << 3);
#pragma unroll
  for (int s = 0; s < 8; s++) {
    rr[s] = prr[base + s];
    ri[s] = pri[base + s];
    cr[s] = pcr[base + s];
    ci[s] = pci[base + s];
    xr[s] = 0.f;
    xi[s] = 0.f;
  }
  float dsk = Dskip[layer * kH + h];

  const float4* up = (const float4*)(uin + ((size_t)g << 10));
  float* yp = yout + ((size_t)g << 10);

  float4 ucur[4], unxt[4];
#pragma unroll
  for (int q = 0; q < 4; q++) ucur[q] = up[q];

  for (int blk = 0; blk < 64; blk++) {  // 64 blocks of 16 time steps
    if (blk < 63) {
#pragma unroll
      for (int q = 0; q < 4; q++) unxt[q] = up[(blk + 1) * 4 + q];
    }
#pragma unroll
    for (int q = 0; q < 4; q++) {
      float keep = 0.f;
#pragma unroll
      for (int i = 0; i < 4; i++) {
        float uu = f4get(ucur[q], i);
#pragma unroll
        for (int s = 0; s < 8; s++) {
          float nxr = fmaf(rr[s], xr[s], fmaf(-ri[s], xi[s], uu));
          float nxi = fmaf(rr[s], xi[s], ri[s] * xr[s]);
          xr[s] = nxr;
          xi[s] = nxi;
        }
        // partial contribution, 2 trees of depth 4
        float t0 = 0.f, t1 = 0.f;
#pragma unroll
        for (int s = 0; s < 4; s++) {
          t0 = fmaf(cr[s], xr[s], fmaf(-ci[s], xi[s], t0));
          t1 = fmaf(cr[s + 4], xr[s + 4], fmaf(-ci[s + 4], xi[s + 4], t1));
        }
        float t = t0 + t1;
        t += __shfl_xor(t, 1);
        t += __shfl_xor(t, 2);
        float y0 = fmaf(dsk, uu, t);
        keep = (i == j) ? y0 : keep;  // lane j keeps step i == j
      }
      // GELU (tanh approx, matches jax.nn.gelu default) on kept value
      float x3 = keep * keep * keep;
      float a = 0.7978845608028654f * fmaf(0.044715f, x3, keep);
      float aa = fminf(a, 15.f);  // avoid exp overflow; tanh(15) ~= 1
      float ex = __expf(2.f * aa);
      float th = 1.f - 2.f / (ex + 1.f);
      yp[blk * 16 + q * 4 + j] = 0.5f * keep * (1.f + th);
    }
#pragma unroll
    for (int q = 0; q < 4; q++) ucur[q] = unxt[q];
  }
}

// ---------------------------------------------------------------------------
// K3: z = Wo @ y + bo per batch, fused GLU: out = z[:H] * sigmoid(z[H:]).
// Block tile: 64 h-rows (both halves) x 128 cols. 256 threads, 4x8 per half.
// ---------------------------------------------------------------------------
__global__ __launch_bounds__(256) void glu_gemm_kernel(
    const float* __restrict__ y,   // (B, H, L)
    const float* __restrict__ Wo,  // (2H, H) this layer
    const float* __restrict__ bo,  // (2H,)  this layer
    float* __restrict__ outp) {    // (B, H, L)
  __shared__ float As1[16][68];
  __shared__ float As2[16][68];
  __shared__ float Bs[16][128];
  int b = blockIdx.z;
  int h0 = blockIdx.y * 64;
  int l0 = blockIdx.x * 128;
  int tid = threadIdx.x;
  int tx = tid & 15, ty = tid >> 4;
  float acc1[4][8] = {}, acc2[4][8] = {};
  const float* yb = y + (size_t)b * kH * kL;

  for (int k0 = 0; k0 < kH; k0 += 16) {
    {
      int kk = tid & 15;  // k fastest -> coalesced 64B rows
      int mm = tid >> 4;
#pragma unroll
      for (int r = 0; r < 4; r++) {
        int m = mm + 16 * r;
        As1[kk][m] = Wo[(size_t)(h0 + m) * kH + k0 + kk];
        As2[kk][m] = Wo[(size_t)(h0 + m + kH) * kH + k0 + kk];
      }
    }
    {
      int nn = tid & 127;
      int kk0 = tid >> 7;  // 0..1
#pragma unroll
      for (int r = 0; r < 8; r++)
        Bs[kk0 + 2 * r][nn] = yb[(size_t)(k0 + kk0 + 2 * r) * kL + l0 + nn];
    }
    __syncthreads();
#pragma unroll
    for (int k = 0; k < 16; k++) {
      float a1[4], a2[4], bb[8];
#pragma unroll
      for (int i = 0; i < 4; i++) {
        a1[i] = As1[k][ty * 4 + i];
        a2[i] = As2[k][ty * 4 + i];
      }
#pragma unroll
      for (int jj = 0; jj < 8; jj++) bb[jj] = Bs[k][tx * 8 + jj];
#pragma unroll
      for (int i = 0; i < 4; i++)
#pragma unroll
        for (int jj = 0; jj < 8; jj++) {
          acc1[i][jj] = fmaf(a1[i], bb[jj], acc1[i][jj]);
          acc2[i][jj] = fmaf(a2[i], bb[jj], acc2[i][jj]);
        }
    }
    __syncthreads();
  }
#pragma unroll
  for (int i = 0; i < 4; i++) {
    int m = h0 + ty * 4 + i;
    float b1 = bo[m], b2 = bo[m + kH];
    float* op = outp + ((size_t)b * kH + m) * kL + l0 + tx * 8;
#pragma unroll
    for (int jj = 0; jj < 8; jj++) {
      float z1 = acc1[i][jj] + b1;
      float z2 = acc2[i][jj] + b2;
      float sg = 1.f / (1.f + __expf(-z2));
      op[jj] = z1 * sg;
    }
  }
}

// ---------------------------------------------------------------------------
// K4: out[b,p,h] = sum_s W_out[p,s] * X[b,h,s] + b_out[p]
// M = P (336, padded tiles), N = H, K = L. 128x128 tile, 8x8 per thread.
// ---------------------------------------------------------------------------
__global__ __launch_bounds__(256) void final_gemm_kernel(
    const float* __restrict__ X,     // (B, H, L)
    const float* __restrict__ Wout,  // (P, L)
    const float* __restrict__ bout,  // (P,)
    float* __restrict__ outp) {      // (B, P, E)
  __shared__ float As[16][132];
  __shared__ float Bs[16][132];
  int b = blockIdx.z;
  int p0 = blockIdx.y * 128;
  int h0 = blockIdx.x * 128;
  int tid = threadIdx.x;
  int tx = tid & 15, ty = tid >> 4;
  float acc[8][8] = {};
  const float* Xb = X + (size_t)b * kH * kL;

  for (int k0 = 0; k0 < kL; k0 += 16) {
    {
      int kk = tid & 15;
      int mm = tid >> 4;
#pragma unroll
      for (int r = 0; r < 8; r++) {
        int m = p0 + mm + 16 * r;
        As[kk][mm + 16 * r] = (m < kP) ? Wout[(size_t)m * kL + k0 + kk] : 0.f;
      }
    }
    {
      int kk = tid & 15;
      int nn0 = tid >> 4;
#pragma unroll
      for (int r = 0; r < 8; r++) {
        int n = nn0 + 16 * r;
        Bs[kk][n] = Xb[(size_t)(h0 + n) * kL + k0 + kk];
      }
    }
    __syncthreads();
#pragma unroll
    for (int k = 0; k < 16; k++) {
      float a[8], bb[8];
#pragma unroll
      for (int i = 0; i < 8; i++) a[i] = As[k][ty * 8 + i];
#pragma unroll
      for (int jj = 0; jj < 8; jj++) bb[jj] = Bs[k][tx * 8 + jj];
#pragma unroll
      for (int i = 0; i < 8; i++)
#pragma unroll
        for (int jj = 0; jj < 8; jj++) acc[i][jj] = fmaf(a[i], bb[jj], acc[i][jj]);
    }
    __syncthreads();
  }
#pragma unroll
  for (int i = 0; i < 8; i++) {
    int p = p0 + ty * 8 + i;
    if (p < kP) {
      float bv = bout[p];
      float* op = outp + ((size_t)b * kP + p) * kH + h0 + tx * 8;
#pragma unroll
      for (int jj = 0; jj < 8; jj++) op[jj] = acc[i][jj] + bv;
    }
  }
}

}  // namespace

extern "C" void kernel_launch(void* const* d_in, const int* in_sizes, int n_in,
                              void* d_out, int out_size, void* d_ws, size_t ws_size,
                              hipStream_t stream) {
  const float* x_enc  = (const float*)d_in[0];
  const float* log_dt = (const float*)d_in[4];
  const float* A_re   = (const float*)d_in[5];
  const float* A_im   = (const float*)d_in[6];
  const float* C_re   = (const float*)d_in[7];
  const float* C_im   = (const float*)d_in[8];
  const float* Dskip  = (const float*)d_in[9];
  const float* Wo     = (const float*)d_in[10];
  const float* bo     = (const float*)d_in[11];
  const float* W_out  = (const float*)d_in[12];
  const float* b_out  = (const float*)d_in[13];
  float* out = (float*)d_out;

  float* ws = (float*)d_ws;
  const size_t ubuf = (size_t)kB * kH * kL;  // 16,777,216 floats
  float* u = ws;
  float* y = ws + ubuf;
  float* prr = ws + 2 * ubuf;
  float* pri = prr + kNL * kH * kNS;
  float* pcr = pri + kNL * kH * kNS;
  float* pci = pcr + kNL * kH * kNS;

  ssm_params_kernel<<<(kNL * kH * kNS + 255) / 256, 256, 0, stream>>>(
      log_dt, A_re, A_im, C_re, C_im, prr, pri, pcr, pci);

  transpose_kernel<<<dim3(kL / 32, kH / 32, kB), dim3(32, 8), 0, stream>>>(x_enc, u);

  for (int layer = 0; layer < kNL; layer++) {
    s4_scan_kernel<<<kB * kH / 64, 256, 0, stream>>>(u, y, prr, pri, pcr, pci, Dskip,
                                                     layer);
    glu_gemm_kernel<<<dim3(kL / 128, kH / 64, kB), 256, 0, stream>>>(
        y, Wo + (size_t)layer * kH2 * kH, bo + (size_t)layer * kH2, u);
  }

  final_gemm_kernel<<<dim3(kH / 128, (kP + 127) / 128, kB), 256, 0, stream>>>(
      u, W_out, b_out, out);
}

// Round 2
// 740.078 us; speedup vs baseline: 2.6926x; 2.6926x over previous
//
#include <hip/hip_runtime.h>
#include <math.h>

typedef _Float16 f16;
typedef f16 f16x8 __attribute__((ext_vector_type(8)));
typedef float f32x4 __attribute__((ext_vector_type(4)));

namespace {

constexpr int kB  = 32;
constexpr int kL  = 1024;
constexpr int kH  = 512;
constexpr int kP  = 336;
constexpr int kNL = 3;
constexpr int kNS = 32;

// async global->LDS, 16B per lane. LDS dest is wave-uniform base + lane*16.
__device__ __forceinline__ void llds16(const void* g, void* s) {
  __builtin_amdgcn_global_load_lds((const __attribute__((address_space(1))) void*)g,
                                   (__attribute__((address_space(3))) void*)s, 16, 0, 0);
}

// ---------------------------------------------------------------------------
// K0: SSM discretization params. r = exp(dt*A); Ct2 = 2*(C * expm1(dt*A)/A)
// ---------------------------------------------------------------------------
__global__ void ssm_params_kernel(const float* __restrict__ log_dt,
                                  const float* __restrict__ A_re,
                                  const float* __restrict__ A_im,
                                  const float* __restrict__ C_re,
                                  const float* __restrict__ C_im,
                                  float* __restrict__ prr, float* __restrict__ pri,
                                  float* __restrict__ pcr, float* __restrict__ pci) {
  int idx = blockIdx.x * blockDim.x + threadIdx.x;
  if (idx >= kNL * kH * kNS) return;
  int lh = idx / kNS;
  float dt = expf(log_dt[lh]);
  float ar = A_re[idx], ai = A_im[idx];
  float dr = dt * ar, di = dt * ai;
  float er = expf(dr);
  float c = cosf(di), s = sinf(di);
  float rr = er * c, ri = er * s;
  float sh = sinf(0.5f * di);
  float mr = expm1f(dr) * c - 2.f * sh * sh;
  float mi = ri;
  float inv = 1.f / (ar * ar + ai * ai);
  float qr = (mr * ar + mi * ai) * inv;
  float qi = (mi * ar - mr * ai) * inv;
  float cre = C_re[idx], cim = C_im[idx];
  prr[idx] = rr;
  pri[idx] = ri;
  pcr[idx] = 2.f * (cre * qr - cim * qi);
  pci[idx] = 2.f * (cre * qi + cim * qr);
}

// ---------------------------------------------------------------------------
// K1: fp32 -> fp16 convert (weights)
// ---------------------------------------------------------------------------
__global__ void f32_to_f16_kernel(const float* __restrict__ s, f16* __restrict__ d,
                                  int n) {
  int i = blockIdx.x * 256 + threadIdx.x;
  if (i < n) d[i] = (f16)s[i];
}

// ---------------------------------------------------------------------------
// K2: (B, L, E) fp32 -> (B, E, L) fp16 transpose
// ---------------------------------------------------------------------------
__global__ __launch_bounds__(256) void transpose_kernel(const float* __restrict__ x,
                                                        f16* __restrict__ u) {
  __shared__ float tile[32][33];
  int b = blockIdx.z;
  int l0 = blockIdx.x * 32, e0 = blockIdx.y * 32;
  int tx = threadIdx.x, ty = threadIdx.y;  // (32, 8)
#pragma unroll
  for (int k = 0; k < 4; k++)
    tile[ty + 8 * k][tx] = x[((size_t)b * kL + (size_t)(l0 + ty + 8 * k)) * kH + e0 + tx];
  __syncthreads();
#pragma unroll
  for (int k = 0; k < 4; k++)
    u[((size_t)b * kH + (size_t)(e0 + ty + 8 * k)) * kL + l0 + tx] =
        (f16)tile[tx][ty + 8 * k];
}

// ---------------------------------------------------------------------------
// K3: diagonal SSM recurrence + D-skip + GELU(tanh). fp16 in (B,H,L),
// fp16 out TRANSPOSED (B,L,H) so the GLU GEMM's B-operand is K-contiguous.
// 4 lanes per (b,h) row, 8 complex states per lane.
// ---------------------------------------------------------------------------
__global__ __launch_bounds__(256) void s4_scan_kernel(
    const f16* __restrict__ uin, f16* __restrict__ yt,
    const float* __restrict__ prr, const float* __restrict__ pri,
    const float* __restrict__ pcr, const float* __restrict__ pci,
    const float* __restrict__ Dskip, int layer) {
  int tid = threadIdx.x;
  int g = (blockIdx.x << 6) + (tid >> 2);  // (b,h) row id
  int j = tid & 3;
  int h = g & (kH - 1);
  int b = g >> 9;

  float rr[8], ri[8], cr[8], ci[8], xr[8], xi[8];
  int base = ((layer * kH + h) << 5) + (j << 3);
#pragma unroll
  for (int s = 0; s < 8; s++) {
    rr[s] = prr[base + s];
    ri[s] = pri[base + s];
    cr[s] = pcr[base + s];
    ci[s] = pci[base + s];
    xr[s] = 0.f;
    xi[s] = 0.f;
  }
  float dsk = Dskip[layer * kH + h];

  const uint4* up = (const uint4*)(uin + ((size_t)g << 10));
  f16* ytb = yt + (size_t)b * kL * kH;

  union U16 {
    uint4 v[2];
    f16 e[16];
  };
  U16 cu, nu;
  cu.v[0] = up[0];
  cu.v[1] = up[1];

  for (int blk = 0; blk < 64; blk++) {
    if (blk < 63) {
      nu.v[0] = up[2 * blk + 2];
      nu.v[1] = up[2 * blk + 3];
    }
#pragma unroll
    for (int q = 0; q < 4; q++) {
      float keep = 0.f;
#pragma unroll
      for (int i = 0; i < 4; i++) {
        float uu = (float)cu.e[q * 4 + i];
#pragma unroll
        for (int s = 0; s < 8; s++) {
          float nxr = fmaf(rr[s], xr[s], fmaf(-ri[s], xi[s], uu));
          float nxi = fmaf(rr[s], xi[s], ri[s] * xr[s]);
          xr[s] = nxr;
          xi[s] = nxi;
        }
        float t0 = 0.f, t1 = 0.f;
#pragma unroll
        for (int s = 0; s < 4; s++) {
          t0 = fmaf(cr[s], xr[s], fmaf(-ci[s], xi[s], t0));
          t1 = fmaf(cr[s + 4], xr[s + 4], fmaf(-ci[s + 4], xi[s + 4], t1));
        }
        float t = t0 + t1;
        t += __shfl_xor(t, 1);
        t += __shfl_xor(t, 2);
        float y0 = fmaf(dsk, uu, t);
        keep = (i == j) ? y0 : keep;
      }
      // GELU (tanh approx)
      float x3 = keep * keep * keep;
      float a = 0.7978845608028654f * fmaf(0.044715f, x3, keep);
      float aa = fminf(a, 15.f);
      float ex = __expf(2.f * aa);
      float th = 1.f - 2.f / (ex + 1.f);
      float val = 0.5f * keep * (1.f + th);
      ytb[(size_t)(blk * 16 + q * 4 + j) * kH + h] = (f16)val;
    }
    cu.v[0] = nu.v[0];
    cu.v[1] = nu.v[1];
  }
}

// ---------------------------------------------------------------------------
// K4: GLU GEMM via MFMA f16. Per block: A-tile = 128 Wo rows (h0..h0+63 of
// half1 and the matching half2 rows), B-tile = 128 l's, K=512 in BK=64 steps.
// LDS is fragment-ordered [subtile][lane][8 halves] -> conflict-free b128
// reads and global_load_lds-compatible (lane-contiguous).
// 4 waves, each 64x64 output; z1/z2 for the same h land in the same lane.
// ---------------------------------------------------------------------------
__global__ __launch_bounds__(256) void glu_mfma_kernel(
    const f16* __restrict__ yt,    // (B, L, H)
    const f16* __restrict__ wo,    // (2H, H) this layer
    const float* __restrict__ bo,  // (2H,)
    f16* __restrict__ uout) {      // (B, H, L)
  __shared__ __align__(16) f16 At[16][64][8];
  __shared__ __align__(16) f16 Bt[16][64][8];
  int tid = threadIdx.x;
  int lane = tid & 63, w = tid >> 6;
  int wm = w >> 1, wn = w & 1;
  int lr = lane & 15, lc = lane >> 4;
  int b = blockIdx.z, h0 = blockIdx.y * 64, l0 = blockIdx.x * 128;
  const f16* ytb = yt + (size_t)b * kL * kH;

  f32x4 acc[4][4] = {};

  const f16* gA[4];
  const f16* gB[4];
#pragma unroll
  for (int i = 0; i < 4; ++i) {
    int st = w * 4 + i, mt = st >> 1, ks = st & 1;
    int row = mt * 16 + lr;
    int hrow = (row < 64) ? (h0 + row) : (448 + h0 + row);  // 512 + h0 + (row-64)
    gA[i] = wo + (size_t)hrow * kH + ks * 32 + lc * 8;
    int lrow = l0 + mt * 16 + lr;
    gB[i] = ytb + (size_t)lrow * kH + ks * 32 + lc * 8;
  }

  for (int k0 = 0; k0 < kH; k0 += 64) {
#pragma unroll
    for (int i = 0; i < 4; ++i) {
      int st = w * 4 + i;
      llds16(gA[i] + k0, &At[st][0][0]);
      llds16(gB[i] + k0, &Bt[st][0][0]);
    }
    __syncthreads();
#pragma unroll
    for (int ks = 0; ks < 2; ++ks) {
      f16x8 av[4], bv[4];
      av[0] = *(const f16x8*)At[(2 * wm + 0) * 2 + ks][lane];
      av[1] = *(const f16x8*)At[(2 * wm + 1) * 2 + ks][lane];
      av[2] = *(const f16x8*)At[(2 * wm + 4) * 2 + ks][lane];
      av[3] = *(const f16x8*)At[(2 * wm + 5) * 2 + ks][lane];
#pragma unroll
      for (int nt = 0; nt < 4; ++nt)
        bv[nt] = *(const f16x8*)Bt[(wn * 4 + nt) * 2 + ks][lane];
#pragma unroll
      for (int i = 0; i < 4; ++i)
#pragma unroll
        for (int nt = 0; nt < 4; ++nt)
          acc[i][nt] =
              __builtin_amdgcn_mfma_f32_16x16x32_f16(av[i], bv[nt], acc[i][nt], 0, 0, 0);
    }
    __syncthreads();
  }

  // epilogue: C/D layout col=lane&15, row=(lane>>4)*4+reg
  int col = lane & 15, q = lane >> 4;
  f16* ub = uout + (size_t)b * kH * kL;
#pragma unroll
  for (int i = 0; i < 2; ++i) {
#pragma unroll
    for (int reg = 0; reg < 4; ++reg) {
      int h = h0 + wm * 32 + i * 16 + q * 4 + reg;
      float b1 = bo[h], b2 = bo[h + kH];
#pragma unroll
      for (int nt = 0; nt < 4; ++nt) {
        float z1 = acc[i][nt][reg] + b1;
        float z2 = acc[i + 2][nt][reg] + b2;
        float sg = 1.f / (1.f + __expf(-z2));
        ub[(size_t)h * kL + l0 + wn * 64 + nt * 16 + col] = (f16)(z1 * sg);
      }
    }
  }
}

// ---------------------------------------------------------------------------
// K5: final projection via MFMA f16. out[b,p,h] = sum_l W[p,l] X[b,h,l] + b[p].
// Block 128 p-rows x 128 h-cols, K = L = 1024.
// ---------------------------------------------------------------------------
__global__ __launch_bounds__(256) void final_mfma_kernel(
    const f16* __restrict__ x,     // (B, H, L)
    const f16* __restrict__ wout,  // (P, L)
    const float* __restrict__ bout,
    float* __restrict__ outp) {  // (B, P, H) fp32
  __shared__ __align__(16) f16 At[16][64][8];
  __shared__ __align__(16) f16 Bt[16][64][8];
  int tid = threadIdx.x;
  int lane = tid & 63, w = tid >> 6;
  int wm = w >> 1, wn = w & 1;
  int lr = lane & 15, lc = lane >> 4;
  int b = blockIdx.z, p0 = blockIdx.y * 128, h0 = blockIdx.x * 128;
  const f16* xb = x + (size_t)b * kH * kL;

  f32x4 acc[4][4] = {};

  const f16* gA[4];
  const f16* gB[4];
#pragma unroll
  for (int i = 0; i < 4; ++i) {
    int st = w * 4 + i, mt = st >> 1, ks = st & 1;
    int prow = p0 + mt * 16 + lr;
    if (prow > kP - 1) prow = kP - 1;  // clamp; masked at store
    gA[i] = wout + (size_t)prow * kL + ks * 32 + lc * 8;
    int hrow = h0 + mt * 16 + lr;
    gB[i] = xb + (size_t)hrow * kL + ks * 32 + lc * 8;
  }

  for (int k0 = 0; k0 < kL; k0 += 64) {
#pragma unroll
    for (int i = 0; i < 4; ++i) {
      int st = w * 4 + i;
      llds16(gA[i] + k0, &At[st][0][0]);
      llds16(gB[i] + k0, &Bt[st][0][0]);
    }
    __syncthreads();
#pragma unroll
    for (int ks = 0; ks < 2; ++ks) {
      f16x8 av[4], bv[4];
#pragma unroll
      for (int i = 0; i < 4; ++i)
        av[i] = *(const f16x8*)At[(wm * 4 + i) * 2 + ks][lane];
#pragma unroll
      for (int nt = 0; nt < 4; ++nt)
        bv[nt] = *(const f16x8*)Bt[(wn * 4 + nt) * 2 + ks][lane];
#pragma unroll
      for (int i = 0; i < 4; ++i)
#pragma unroll
        for (int nt = 0; nt < 4; ++nt)
          acc[i][nt] =
              __builtin_amdgcn_mfma_f32_16x16x32_f16(av[i], bv[nt], acc[i][nt], 0, 0, 0);
    }
    __syncthreads();
  }

  int col = lane & 15, q = lane >> 4;
  float* ob = outp + (size_t)b * kP * kH;
#pragma unroll
  for (int i = 0; i < 4; ++i) {
#pragma unroll
    for (int reg = 0; reg < 4; ++reg) {
      int p = p0 + wm * 64 + i * 16 + q * 4 + reg;
      if (p < kP) {
        float bv2 = bout[p];
#pragma unroll
        for (int nt = 0; nt < 4; ++nt)
          ob[(size_t)p * kH + h0 + wn * 64 + nt * 16 + col] = acc[i][nt][reg] + bv2;
      }
    }
  }
}

}  // namespace

extern "C" void kernel_launch(void* const* d_in, const int* in_sizes, int n_in,
                              void* d_out, int out_size, void* d_ws, size_t ws_size,
                              hipStream_t stream) {
  const float* x_enc  = (const float*)d_in[0];
  const float* log_dt = (const float*)d_in[4];
  const float* A_re   = (const float*)d_in[5];
  const float* A_im   = (const float*)d_in[6];
  const float* C_re   = (const float*)d_in[7];
  const float* C_im   = (const float*)d_in[8];
  const float* Dskip  = (const float*)d_in[9];
  const float* Wo     = (const float*)d_in[10];
  const float* bo     = (const float*)d_in[11];
  const float* W_out  = (const float*)d_in[12];
  const float* b_out  = (const float*)d_in[13];
  float* out = (float*)d_out;

  char* wsb = (char*)d_ws;
  f16* u16    = (f16*)(wsb);                  // 32 MB  (B,H,L)
  f16* yt16   = (f16*)(wsb + 33554432);       // 32 MB  (B,L,H)
  f16* wo16   = (f16*)(wsb + 67108864);       // 3 MB   (NL,2H,H)
  f16* wout16 = (f16*)(wsb + 70254592);       // 672 KB (P,L)
  float* prr  = (float*)(wsb + 70942720);
  float* pri  = prr + kNL * kH * kNS;
  float* pcr  = pri + kNL * kH * kNS;
  float* pci  = pcr + kNL * kH * kNS;

  const int nwo = kNL * 2 * kH * kH;  // 1,572,864
  const int nwp = kP * kL;            // 344,064
  f32_to_f16_kernel<<<(nwo + 255) / 256, 256, 0, stream>>>(Wo, wo16, nwo);
  f32_to_f16_kernel<<<(nwp + 255) / 256, 256, 0, stream>>>(W_out, wout16, nwp);

  ssm_params_kernel<<<(kNL * kH * kNS + 255) / 256, 256, 0, stream>>>(
      log_dt, A_re, A_im, C_re, C_im, prr, pri, pcr, pci);

  transpose_kernel<<<dim3(kL / 32, kH / 32, kB), dim3(32, 8), 0, stream>>>(x_enc, u16);

  for (int layer = 0; layer < kNL; layer++) {
    s4_scan_kernel<<<kB * kH / 64, 256, 0, stream>>>(u16, yt16, prr, pri, pcr, pci,
                                                     Dskip, layer);
    glu_mfma_kernel<<<dim3(kL / 128, kH / 64, kB), 256, 0, stream>>>(
        yt16, wo16 + (size_t)layer * 2 * kH * kH, bo + (size_t)layer * 2 * kH, u16);
  }

  final_mfma_kernel<<<dim3(kH / 128, 3, kB), 256, 0, stream>>>(u16, wout16, b_out, out);
}